// Round 6
// baseline (24.236 us; speedup 1.0000x reference)
//
#include <hip/hip_runtime.h>

// Triple softmax along keys == uniform(1/S) to ~1e-7, so
//   out[b,s,:] = ((mean_s' v[b,s',:]) @ Wv.T + bv) @ Wo.T + bo
// independent of q, k, Wq, Wk, padding_mask, s. Measured absmax 2.4e-4
// (threshold 2.34e-3) rounds 1-5.
//
// Round 6: R5 (21.9us, 5 dispatches) minus one gap: fuse matvec2+broadcast
// with ZERO redundancy (every redundant-traffic fusion regressed: R2 +3.6,
// R4 +8.7). K4 block = 16-column n-chunk (one 64B line per out row): computes
// its r slice (Wo read once chip-wide), then writes its columns for all
// 4096 (b,s) rows as full-line float4 stores.
//   K1 colsum partial  (128 blk, 32 rows each, nt float4)
//   K2 finalize vmean  (32 blk, 16 KB each, LDS tree)
//   K3 t = vmean@Wv.T + bv (256 blk, wave = one Wv row x 4 batches)
//   K4 r = t@Wo.T + bo fused with broadcast (64 blk, zero redundancy)

#define BATCH 4
#define SEQ 1024
#define DIM 1024
#define D4 256            // float4 per row
#define RCH 32            // K1 row-chunks (32 rows each)

typedef float f32x4 __attribute__((ext_vector_type(4)));

// ---- K1: part[b][rc][:] = sum of 32 rows of v. grid (4,32), 256 thr ----
__global__ void __launch_bounds__(256) k1_colsum(const f32x4* __restrict__ v4,
                                                 f32x4* __restrict__ part) {
    const int b = blockIdx.x, rc = blockIdx.y, tid = threadIdx.x;
    const f32x4* p = v4 + (size_t)(b * SEQ + rc * 32) * D4 + tid;
    f32x4 s = {0.f, 0.f, 0.f, 0.f};
#pragma unroll
    for (int i = 0; i < 32; ++i) s += __builtin_nontemporal_load(p + i * D4);
    part[(size_t)(b * RCH + rc) * D4 + tid] = s;
}

// ---- K2: vmean[b][:] = (1/SEQ)*sum_rc part. grid 32, 256 thr ----
// block = (b, col-chunk of 32 f4); thread = (col 0..31, group 0..7);
// group g sums 4 of the 32 chunks. 16 KB read per block, zero redundancy.
__global__ void __launch_bounds__(256) k2_final(const f32x4* __restrict__ part,
                                                f32x4* __restrict__ vmean) {
    __shared__ f32x4 sh[8][32];
    const int b = blockIdx.x >> 3, cq = blockIdx.x & 7;
    const int col = cq * 32 + (threadIdx.x & 31);
    const int g   = threadIdx.x >> 5;
    const f32x4* p = part + (size_t)(b * RCH + g * 4) * D4 + col;
    f32x4 s = p[0] + p[D4] + p[2 * D4] + p[3 * D4];
    sh[g][threadIdx.x & 31] = s;
    __syncthreads();
    if (threadIdx.x < 32) {
        f32x4 t = sh[0][threadIdx.x];
#pragma unroll
        for (int j = 1; j < 8; ++j) t += sh[j][threadIdx.x];
        t *= (1.0f / SEQ);
        vmean[(size_t)b * D4 + cq * 32 + threadIdx.x] = t;
    }
}

// ---- K3: t[b][n] = bv[n] + vmean[b]·Wv[n]. grid 256, 256 thr ----
__global__ void __launch_bounds__(256) k3_matvec(const f32x4* __restrict__ x4,
                                                 const f32x4* __restrict__ W4,
                                                 const float* __restrict__ bias,
                                                 float* __restrict__ y) {
    __shared__ f32x4 sh[4 * D4];
#pragma unroll
    for (int k = 0; k < 4; ++k)
        sh[k * D4 + threadIdx.x] = x4[k * D4 + threadIdx.x];
    __syncthreads();

    const int wv = threadIdx.x >> 6, lane = threadIdx.x & 63;
    const int n = blockIdx.x * 4 + wv;
    const f32x4* wrow = W4 + (size_t)n * D4;
    float a0 = 0.f, a1 = 0.f, a2 = 0.f, a3 = 0.f;
#pragma unroll
    for (int it = 0; it < 4; ++it) {
        const int col = it * 64 + lane;
        const f32x4 w  = __builtin_nontemporal_load(wrow + col);
        const f32x4 x0 = sh[col];
        const f32x4 x1 = sh[D4 + col];
        const f32x4 x2 = sh[2 * D4 + col];
        const f32x4 x3 = sh[3 * D4 + col];
        a0 += w.x * x0.x + w.y * x0.y + w.z * x0.z + w.w * x0.w;
        a1 += w.x * x1.x + w.y * x1.y + w.z * x1.z + w.w * x1.w;
        a2 += w.x * x2.x + w.y * x2.y + w.z * x2.z + w.w * x2.w;
        a3 += w.x * x3.x + w.y * x3.y + w.z * x3.z + w.w * x3.w;
    }
#pragma unroll
    for (int off = 32; off > 0; off >>= 1) {
        a0 += __shfl_down(a0, off);
        a1 += __shfl_down(a1, off);
        a2 += __shfl_down(a2, off);
        a3 += __shfl_down(a3, off);
    }
    if (lane == 0) {
        const float bb = bias[n];
        y[0 * DIM + n] = a0 + bb;
        y[1 * DIM + n] = a1 + bb;
        y[2 * DIM + n] = a2 + bb;
        y[3 * DIM + n] = a3 + bb;
    }
}

// ---- K4: fused r = t@Wo.T + bo AND broadcast. grid 64, 256 thr ----
// Block nb owns columns [nb*16, nb*16+16): computes r[b][those] for all 4 b
// (each Wo row read once chip-wide), then writes those 16 columns (= one
// 64B line per out row) for all 4096 (b,s) rows. Zero redundant traffic.
__global__ void __launch_bounds__(256) k4_out(const f32x4* __restrict__ t4,
                                              const f32x4* __restrict__ Wo4,
                                              const float* __restrict__ bo,
                                              f32x4* __restrict__ out4) {
    __shared__ f32x4 sh[4 * D4];              // staged t, 16 KB
    __shared__ alignas(16) float shr[4][16];  // r slice
    const int tid = threadIdx.x;
    const int nb  = blockIdx.x;               // 0..63
#pragma unroll
    for (int k = 0; k < 4; ++k) sh[k * D4 + tid] = t4[k * D4 + tid];
    __syncthreads();

    const int wv = tid >> 6, lane = tid & 63;
#pragma unroll
    for (int i = 0; i < 4; ++i) {
        const int nl = wv * 4 + i;            // 0..15
        const int n  = nb * 16 + nl;
        const f32x4* wrow = Wo4 + (size_t)n * D4;
        float a0 = 0.f, a1 = 0.f, a2 = 0.f, a3 = 0.f;
#pragma unroll
        for (int it = 0; it < 4; ++it) {
            const int col = it * 64 + lane;
            const f32x4 w  = __builtin_nontemporal_load(wrow + col);
            const f32x4 x0 = sh[col];
            const f32x4 x1 = sh[D4 + col];
            const f32x4 x2 = sh[2 * D4 + col];
            const f32x4 x3 = sh[3 * D4 + col];
            a0 += w.x * x0.x + w.y * x0.y + w.z * x0.z + w.w * x0.w;
            a1 += w.x * x1.x + w.y * x1.y + w.z * x1.z + w.w * x1.w;
            a2 += w.x * x2.x + w.y * x2.y + w.z * x2.z + w.w * x2.w;
            a3 += w.x * x3.x + w.y * x3.y + w.z * x3.z + w.w * x3.w;
        }
#pragma unroll
        for (int off = 32; off > 0; off >>= 1) {
            a0 += __shfl_down(a0, off);
            a1 += __shfl_down(a1, off);
            a2 += __shfl_down(a2, off);
            a3 += __shfl_down(a3, off);
        }
        if (lane == 0) {
            const float bb = bo[n];
            shr[0][nl] = a0 + bb;
            shr[1][nl] = a1 + bb;
            shr[2][nl] = a2 + bb;
            shr[3][nl] = a3 + bb;
        }
    }
    __syncthreads();

    // Broadcast: thread = (pair-group pg 0..63, f4 index f4i 0..3).
    // 4 lanes cover one full 64B line of out row (b,s).
    const f32x4* r4 = (const f32x4*)shr;      // r4[b*4 + f4i]
    const int f4i = tid & 3, pg = tid >> 2;
    const f32x4 vb0 = r4[0 * 4 + f4i];
    const f32x4 vb1 = r4[1 * 4 + f4i];
    const f32x4 vb2 = r4[2 * 4 + f4i];
    const f32x4 vb3 = r4[3 * 4 + f4i];
    const size_t cbase = (size_t)nb * 4 + f4i;
#pragma unroll
    for (int it = 0; it < 64; ++it) {
        const int b = it >> 4;                           // uniform per it
        const int s = (it & 15) * 64 + pg;
        const f32x4 val = (b == 0) ? vb0 : (b == 1) ? vb1 : (b == 2) ? vb2 : vb3;
        __builtin_nontemporal_store(val,
            out4 + (size_t)(b * SEQ + s) * D4 + cbase);
    }
}

extern "C" void kernel_launch(void* const* d_in, const int* in_sizes, int n_in,
                              void* d_out, int out_size, void* d_ws, size_t ws_size,
                              hipStream_t stream) {
    const f32x4* v4  = (const f32x4*)d_in[2];
    const f32x4* Wv4 = (const f32x4*)d_in[8];
    const float* bv  = (const float*)d_in[9];
    const f32x4* Wo4 = (const f32x4*)d_in[10];
    const float* bo  = (const float*)d_in[11];
    f32x4* out4 = (f32x4*)d_out;

    float* ws = (float*)d_ws;
    f32x4* part  = (f32x4*)ws;                        // 4*32*1024 fl = 512 KB
    float* vmean = ws + (size_t)BATCH * RCH * DIM;    // 4096 floats
    float* t     = vmean + (size_t)BATCH * DIM;       // 4096 floats

    k1_colsum<<<dim3(BATCH, RCH), 256, 0, stream>>>(v4, part);
    k2_final<<<32, 256, 0, stream>>>(part, (f32x4*)vmean);
    k3_matvec<<<256, 256, 0, stream>>>((const f32x4*)vmean, Wv4, bv, t);
    k4_out<<<64, 256, 0, stream>>>((const f32x4*)t, Wo4, bo, out4);
}

// Round 7
// 21.487 us; speedup vs baseline: 1.1279x; 1.1279x over previous
//
#include <hip/hip_runtime.h>

// Triple softmax along keys == uniform(1/S) to ~1e-7, so
//   out[b,s,:] = ((mean_s' v[b,s',:]) @ Wv.T + bv) @ Wo.T + bo
// independent of q, k, Wq, Wk, padding_mask, s. Measured absmax 2.4e-4
// (threshold 2.34e-3) rounds 1-6.
//
// Round 7: R5's zero-redundancy 5-dispatch chain (best: 21.9us) + micro:
//  - K1: regular (not nt) part store -> K2 hits L2
//  - K2: 64 blocks, 8-deep load chains (was 32 blocks / 16-deep)
//  - K3/K4: register-staged x (no LDS, no __syncthreads), 20 indep loads/lane
//  - K5: unchanged (1024 blocks, nt stores)
// Structure is forced: fusions either add redundant traffic (R2 +3.6us,
// R4 +8.7us) or starve a BW phase's grid (R6 +2.3us); grid.sync ~50us (R3).

#define BATCH 4
#define SEQ 1024
#define DIM 1024
#define D4 256            // float4 per row
#define RCH 128           // K1 row-chunks (8 rows each)

typedef float f32x4 __attribute__((ext_vector_type(4)));

// ---- K1: part[b][rc][:] = sum of 8 rows of v. grid (4,128), 256 thr ----
__global__ void __launch_bounds__(256) k1_colsum(const f32x4* __restrict__ v4,
                                                 f32x4* __restrict__ part) {
    const int b = blockIdx.x, rc = blockIdx.y, tid = threadIdx.x;
    const f32x4* p = v4 + (size_t)(b * SEQ + rc * 8) * D4 + tid;
    f32x4 s = {0.f, 0.f, 0.f, 0.f};
#pragma unroll
    for (int i = 0; i < 8; ++i) s += __builtin_nontemporal_load(p + i * D4);
    part[(size_t)(b * RCH + rc) * D4 + tid] = s;    // regular store: K2 reads it
}

// ---- K2: vmean[b][:] = (1/SEQ)*sum_rc part. grid (4,16)=64 blk, 256 thr ----
// block = (b, col-chunk of 16 f4); thread = (col 0..15, group g 0..15);
// group g sums partial rows [g*8, g*8+8). Zero redundancy.
__global__ void __launch_bounds__(256) k2_final(const f32x4* __restrict__ part,
                                                f32x4* __restrict__ vmean) {
    __shared__ f32x4 sh[16][16];
    const int b = blockIdx.x, cq = blockIdx.y;
    const int c = threadIdx.x & 15, g = threadIdx.x >> 4;
    const int col = cq * 16 + c;
    const f32x4* p = part + (size_t)(b * RCH + g * 8) * D4 + col;
    f32x4 s = {0.f, 0.f, 0.f, 0.f};
#pragma unroll
    for (int i = 0; i < 8; ++i) s += p[i * D4];
    sh[g][c] = s;
    __syncthreads();
    if (threadIdx.x < 16) {
        f32x4 t = sh[0][threadIdx.x];
#pragma unroll
        for (int j = 1; j < 16; ++j) t += sh[j][threadIdx.x];
        t *= (1.0f / SEQ);
        vmean[(size_t)b * D4 + cq * 16 + threadIdx.x] = t;
    }
}

// ---- K3/K4: y[b][n] = bias[n] + x[b]·W[n]. grid 256, 256 thr ----
// wave = one W row dotted against all 4 batches (W read exactly once).
// x staged in REGISTERS (16 indep loads/lane), no LDS, no barrier.
__global__ void __launch_bounds__(256) k_matvec(const f32x4* __restrict__ x4,
                                                const f32x4* __restrict__ W4,
                                                const float* __restrict__ bias,
                                                float* __restrict__ y) {
    const int wv = threadIdx.x >> 6, lane = threadIdx.x & 63;
    const int n = blockIdx.x * 4 + wv;
    const f32x4* wrow = W4 + (size_t)n * D4;

    f32x4 w[4], xv[4][4];
#pragma unroll
    for (int it = 0; it < 4; ++it) {
        const int col = it * 64 + lane;
        w[it] = __builtin_nontemporal_load(wrow + col);
#pragma unroll
        for (int bb = 0; bb < 4; ++bb) xv[bb][it] = x4[bb * D4 + col];
    }

    float a0 = 0.f, a1 = 0.f, a2 = 0.f, a3 = 0.f;
#pragma unroll
    for (int it = 0; it < 4; ++it) {
        a0 += w[it].x * xv[0][it].x + w[it].y * xv[0][it].y
            + w[it].z * xv[0][it].z + w[it].w * xv[0][it].w;
        a1 += w[it].x * xv[1][it].x + w[it].y * xv[1][it].y
            + w[it].z * xv[1][it].z + w[it].w * xv[1][it].w;
        a2 += w[it].x * xv[2][it].x + w[it].y * xv[2][it].y
            + w[it].z * xv[2][it].z + w[it].w * xv[2][it].w;
        a3 += w[it].x * xv[3][it].x + w[it].y * xv[3][it].y
            + w[it].z * xv[3][it].z + w[it].w * xv[3][it].w;
    }
#pragma unroll
    for (int off = 32; off > 0; off >>= 1) {
        a0 += __shfl_down(a0, off);
        a1 += __shfl_down(a1, off);
        a2 += __shfl_down(a2, off);
        a3 += __shfl_down(a3, off);
    }
    if (lane == 0) {
        const float bb = bias[n];
        y[0 * DIM + n] = a0 + bb;
        y[1 * DIM + n] = a1 + bb;
        y[2 * DIM + n] = a2 + bb;
        y[3 * DIM + n] = a3 + bb;
    }
}

// ---- K5: broadcast r to out. grid (4,256)=1024 blk, 256 thr; 4 s-rows ----
__global__ void __launch_bounds__(256) k5_bcast(const f32x4* __restrict__ r4,
                                                f32x4* __restrict__ out4) {
    const int b = blockIdx.x, sch = blockIdx.y, tid = threadIdx.x;
    const f32x4 val = r4[(size_t)b * D4 + tid];
    f32x4* o = out4 + (size_t)(b * SEQ + sch * 4) * D4 + tid;
#pragma unroll
    for (int k = 0; k < 4; ++k) __builtin_nontemporal_store(val, o + k * D4);
}

extern "C" void kernel_launch(void* const* d_in, const int* in_sizes, int n_in,
                              void* d_out, int out_size, void* d_ws, size_t ws_size,
                              hipStream_t stream) {
    const f32x4* v4  = (const f32x4*)d_in[2];
    const f32x4* Wv4 = (const f32x4*)d_in[8];
    const float* bv  = (const float*)d_in[9];
    const f32x4* Wo4 = (const f32x4*)d_in[10];
    const float* bo  = (const float*)d_in[11];
    f32x4* out4 = (f32x4*)d_out;

    float* ws = (float*)d_ws;
    f32x4* part  = (f32x4*)ws;                        // 4*128*1024 fl = 2 MB
    float* vmean = ws + (size_t)BATCH * RCH * DIM;    // 4096 floats
    float* t     = vmean + (size_t)BATCH * DIM;       // 4096 floats
    float* r     = t + (size_t)BATCH * DIM;           // 4096 floats

    k1_colsum<<<dim3(BATCH, RCH), 256, 0, stream>>>(v4, part);
    k2_final<<<dim3(BATCH, 16), 256, 0, stream>>>(part, (f32x4*)vmean);
    k_matvec<<<256, 256, 0, stream>>>((const f32x4*)vmean, Wv4, bv, t);
    k_matvec<<<256, 256, 0, stream>>>((const f32x4*)t, Wo4, bo, r);
    k5_bcast<<<dim3(BATCH, 256), 256, 0, stream>>>((const f32x4*)r, out4);
}